// Round 12
// baseline (360.277 us; speedup 1.0000x reference)
//
#include <hip/hip_runtime.h>
#include <hip/hip_bf16.h>

// Switch-Transformer FFN, top-1 routing. B=4,S=4096,D=1024,F=2048,E=8.
// Pipeline: router_logits(+x->bf16) | bucketize | W1/W2 transpose->bf16 |
// grouped GEMM1 (gathered A, GELU, h bf16 dense by slot) |
// grouped GEMM2 (dense A, scale epi, scatter fp32).
// GEMM (m201-geometry): 256x256 tile, BK=64, 8 waves (2x4), wave 128x64,
// acc[8][4], LDS dbuf-2 (133KB, 1 block/CU). 4 phases/K-step, each
// {ds-frags | stage | bar | setprio 16 MFMA | bar}; stages at ph0/ph1,
// vmcnt(0) at ph3 (stages 2-3 phases old -> drain hidden). LDS/MFMA pipes
// balanced at this geometry (FLOP/LDS-byte = 42.7 vs 25.6 at 128x32).

typedef __attribute__((ext_vector_type(8))) short short8;
typedef __attribute__((ext_vector_type(4))) float f32x4;

struct __align__(8) us4 { unsigned short x, y, z, w; };

__device__ __forceinline__ void gload16(const void* g, void* l) {
  __builtin_amdgcn_global_load_lds(
      (const __attribute__((address_space(1))) unsigned int*)g,
      (__attribute__((address_space(3))) unsigned int*)l, 16, 0, 0);
}

__device__ __forceinline__ unsigned short f2b(float f) {
  union { float f; unsigned u; } v; v.f = f;
  unsigned r = v.u + 0x7FFFu + ((v.u >> 16) & 1u);   // RNE
  return (unsigned short)(r >> 16);
}

// ---------------- router: logits, softmax top-1, expert id, x->bf16 ---------
__global__ __launch_bounds__(256) void router_logits(
    const float* __restrict__ x, const float* __restrict__ Wr,
    const float* __restrict__ br, float* __restrict__ wts,
    int* __restrict__ eidx, unsigned short* __restrict__ xb)
{
  const int lane = threadIdx.x & 63;
  const int wid  = threadIdx.x >> 6;
  const int t = blockIdx.x * 4 + wid;

  const float4* x4 = (const float4*)(x + (size_t)t * 1024);
  float acc[8];
#pragma unroll
  for (int e = 0; e < 8; ++e) acc[e] = 0.f;
#pragma unroll
  for (int i = 0; i < 4; ++i) {
    float4 v = x4[lane + 64 * i];
    const int d = (lane + 64 * i) * 4;
    const float* wr = Wr + (size_t)d * 8;
    float xs[4] = {v.x, v.y, v.z, v.w};
    us4 o;
    o.x = f2b(v.x); o.y = f2b(v.y); o.z = f2b(v.z); o.w = f2b(v.w);
    *(us4*)(xb + (size_t)t * 1024 + (size_t)(lane + 64 * i) * 4) = o;
#pragma unroll
    for (int j = 0; j < 4; ++j) {
      float4 w0 = *(const float4*)(wr + j * 8);
      float4 w1 = *(const float4*)(wr + j * 8 + 4);
      acc[0] += xs[j] * w0.x; acc[1] += xs[j] * w0.y;
      acc[2] += xs[j] * w0.z; acc[3] += xs[j] * w0.w;
      acc[4] += xs[j] * w1.x; acc[5] += xs[j] * w1.y;
      acc[6] += xs[j] * w1.z; acc[7] += xs[j] * w1.w;
    }
  }
#pragma unroll
  for (int e = 0; e < 8; ++e) {
    float v = acc[e];
#pragma unroll
    for (int m = 32; m; m >>= 1) v += __shfl_xor(v, m, 64);
    acc[e] = v;
  }
  if (lane == 0) {
    float lg[8];
#pragma unroll
    for (int e = 0; e < 8; ++e) lg[e] = acc[e] + br[e];
    float mx = lg[0]; int bi = 0;
#pragma unroll
    for (int e = 1; e < 8; ++e) if (lg[e] > mx) { mx = lg[e]; bi = e; }  // first-max == argmax
    float s = 0.f;
#pragma unroll
    for (int e = 0; e < 8; ++e) s += expf(lg[e] - mx);
    wts[t]  = 1.0f / s;
    eidx[t] = bi;
  }
}

// ---------------- bucketize ----------
__global__ __launch_bounds__(256) void bucketize(
    const int* __restrict__ eidx, int* __restrict__ cnt, int* __restrict__ list)
{
  __shared__ int lcnt[8], base[8];
  const int tid = threadIdx.x;
  if (tid < 8) lcnt[tid] = 0;
  __syncthreads();
  const int t = blockIdx.x * 256 + tid;
  const int e = eidx[t];
  const int lpos = atomicAdd(&lcnt[e], 1);
  __syncthreads();
  if (tid < 8) base[tid] = atomicAdd(&cnt[tid], lcnt[tid]);
  __syncthreads();
  list[e * 16384 + base[e] + lpos] = t;
}

// ---------------- W[k][n] fp32 -> Wt[n][k] bf16 ----------
__global__ __launch_bounds__(256) void transpose_cvt(
    const float* __restrict__ W, unsigned short* __restrict__ Wt, int K, int N)
{
  __shared__ float tl[64][65];
  const int e = blockIdx.z;
  const float* Wp = W + (size_t)e * K * N;
  unsigned short* Wtp = Wt + (size_t)e * K * N;
  const int k0 = blockIdx.y * 64, n0 = blockIdx.x * 64;
  const int r = threadIdx.x >> 4, c4 = (threadIdx.x & 15) * 4;
#pragma unroll
  for (int i = 0; i < 4; ++i) {
    float4 v = *(const float4*)(Wp + (size_t)(k0 + r + i * 16) * N + n0 + c4);
    tl[r + i * 16][c4 + 0] = v.x; tl[r + i * 16][c4 + 1] = v.y;
    tl[r + i * 16][c4 + 2] = v.z; tl[r + i * 16][c4 + 3] = v.w;
  }
  __syncthreads();
#pragma unroll
  for (int i = 0; i < 4; ++i) {
    const int n = r + i * 16;
    us4 o;
    o.x = f2b(tl[c4 + 0][n]); o.y = f2b(tl[c4 + 1][n]);
    o.z = f2b(tl[c4 + 2][n]); o.w = f2b(tl[c4 + 3][n]);
    *(us4*)(Wtp + (size_t)(n0 + n) * K + k0 + c4) = o;
  }
}

// ---------------- grouped GEMM: 256x256, BK=64, 4-phase, dbuf-2 -------------
// LDS (133120 B): A dbuf 2x32KB @0; B dbuf 2x32KB @65536; tok@131072
// wt@132096. Rows are 128B (64 k); XOR swizzle: physical 16B-slot s of row r
// holds global chunk s^(r&7). Stage: lane l of an issue covers row
// base+(l>>3), phys slot l&7 -> source chunk (l&7)^(l>>3) (rule 21).
// Per K-step T (buf=T&1), 4 phases (frag lifetimes minimized):
//   ph0: ds A m0-3 k01 (8) + B n01 k01 (4); STG_A(T+1); BAR | 16 MFMA m03xn01 | BAR
//   ph1: ds B n23 k01 (4);                  STG_B(T+1); BAR | 16 MFMA m03xn23 | BAR
//   ph2: ds A m4-7 k01 (8);                              BAR | 16 MFMA m47xn23 | BAR
//   ph3: vmcnt(0) [stages 2-3 phases old];               BAR | 16 MFMA m47xn01 | BAR
template <int K, int N, int EPI, int LOGNB>
__global__ __launch_bounds__(512, 2) void gemm_moe8(
    const unsigned short* __restrict__ A,    // EPI1: xb[16384][K] (token rows)
                                             // EPI2: h [16384][K] (slot rows)
    const unsigned short* __restrict__ Bt,   // [8][N][K] bf16
    const float* __restrict__ bias,          // [8][N]
    const int* __restrict__ cnt, const int* __restrict__ list,
    const float* __restrict__ wts, void* __restrict__ outp)
{
  constexpr int NT = K / 64;
  constexpr int NB = 1 << LOGNB;
  extern __shared__ char lds[];
  int*   tok_s = (int*)(lds + 131072);
  float* wt_s  = (float*)(lds + 132096);

  // ---- decode: XCD-chunked p -> (expert, mb, nb); nb fast (A-panel reuse)
  const int q = gridDim.x >> 3;
  const int p = ((int)blockIdx.x & 7) * q + ((int)blockIdx.x >> 3);
  int e = -1, pre = 0, cnte = 0, loc = p;
#pragma unroll
  for (int i = 0; i < 8; ++i) {
    const int c = cnt[i];
    const int bl = ((c + 255) >> 8) << LOGNB;
    if (e < 0) {
      if (loc < bl) { e = i; cnte = c; }
      else { loc -= bl; pre += c; }
    }
  }
  if (e < 0) return;
  const int row0 = (loc >> LOGNB) << 8;      // BM=256
  const int n0   = (loc & (NB - 1)) << 8;    // BN=256

  const int tid = threadIdx.x;
  const int lane = tid & 63, wid = tid >> 6;
  const int wr = wid >> 2, wc = wid & 3;     // wave output: rows wr*128, cols wc*64
  const int l15 = lane & 15, hi = lane >> 4;

  if (tid < 256) {
    const int s = row0 + tid;
    if (s < cnte) {
      const int t = list[e * 16384 + s];
      tok_s[tid] = t;
      wt_s[tid]  = (EPI == 2) ? wts[t] : 0.f;
    } else { tok_s[tid] = 0; wt_s[tid] = 0.f; }
  }
  __syncthreads();

  // ---- staging sources: 4 issues each for A and B; issue k covers rows
  // wid*8 + (lane>>3) + k*64; phys slot lane&7 -> src chunk (lane&7)^(lane>>3)
  const int r8 = lane >> 3;
  const int ch = (lane & 7) ^ r8;            // pre-swizzled source chunk
  const unsigned short* aP[4];
  const unsigned short* bP[4];
#pragma unroll
  for (int k2 = 0; k2 < 4; ++k2) {
    const int row = wid * 8 + r8 + k2 * 64;
    if (EPI == 1) aP[k2] = A + (size_t)tok_s[row] * K + ch * 8;
    else          aP[k2] = A + (size_t)min(pre + row0 + row, 16383) * K + ch * 8;
    bP[k2] = Bt + ((size_t)e * N + n0 + row) * K + ch * 8;
  }

  // ---- fragment read bases: addr = row*128 + ((kc*4+hi)^(row&7))*16,
  // row&7 = l15&7 (wr*128, wc*64, m*16, n*16 all ≡0 mod 8)
  const int sl0 = ((hi ^ (l15 & 7)) << 4);            // kc=0
  const int sl1 = (((4 + hi) ^ (l15 & 7)) << 4);      // kc=1
  const char* aR0 = lds + (size_t)(wr * 128 + l15) * 128 + sl0;
  const char* aR1 = lds + (size_t)(wr * 128 + l15) * 128 + sl1;
  const char* bR0 = lds + 65536 + (size_t)(wc * 64 + l15) * 128 + sl0;
  const char* bR1 = lds + 65536 + (size_t)(wc * 64 + l15) * 128 + sl1;

  f32x4 acc[8][4];
#pragma unroll
  for (int m = 0; m < 8; ++m)
#pragma unroll
    for (int n = 0; n < 4; ++n) acc[m][n] = (f32x4){0.f, 0.f, 0.f, 0.f};

#define STG_A(BUF, T) do { _Pragma("unroll") \
    for (int k2 = 0; k2 < 4; ++k2) \
      gload16(aP[k2] + (size_t)(T) * 64, lds + (BUF) * 32768 + wid * 1024 + k2 * 8192); \
  } while (0)
#define STG_B(BUF, T) do { _Pragma("unroll") \
    for (int k2 = 0; k2 < 4; ++k2) \
      gload16(bP[k2] + (size_t)(T) * 64, lds + 65536 + (BUF) * 32768 + wid * 1024 + k2 * 8192); \
  } while (0)
#define BARF() do { __builtin_amdgcn_s_barrier(); asm volatile("" ::: "memory"); } while (0)

  // ---- prologue: stage K-step 0 into buf 0
  STG_A(0, 0); STG_B(0, 0);
  asm volatile("s_waitcnt vmcnt(0)" ::: "memory");
  BARF();

  short8 aF[8], bA[4], bB[4];
#pragma unroll 1
  for (int T = 0; T < NT; ++T) {
    const int buf = T & 1, bufn = buf ^ 1;
    const int Ts = (T + 1 < NT) ? T + 1 : NT - 1;     // dummy restage at tail
    const char* a0 = aR0 + buf * 32768;
    const char* a1 = aR1 + buf * 32768;
    const char* b0 = bR0 + buf * 32768;
    const char* b1 = bR1 + buf * 32768;

    // ---- ph0: A m0-3, B n0-1; stage A(T+1); MFMA m0-3 x n0-1
#pragma unroll
    for (int m = 0; m < 4; ++m) {
      aF[2 * m]     = *(const short8*)(a0 + m * 2048);
      aF[2 * m + 1] = *(const short8*)(a1 + m * 2048);
    }
#pragma unroll
    for (int n = 0; n < 2; ++n) {
      bA[2 * n]     = *(const short8*)(b0 + n * 2048);
      bA[2 * n + 1] = *(const short8*)(b1 + n * 2048);
    }
    STG_A(bufn, Ts);
    BARF();
    __builtin_amdgcn_s_setprio(1);
#pragma unroll
    for (int m = 0; m < 4; ++m)
#pragma unroll
      for (int n = 0; n < 2; ++n) {
        acc[m][n] = __builtin_amdgcn_mfma_f32_16x16x32_bf16(aF[2 * m], bA[2 * n], acc[m][n], 0, 0, 0);
        acc[m][n] = __builtin_amdgcn_mfma_f32_16x16x32_bf16(aF[2 * m + 1], bA[2 * n + 1], acc[m][n], 0, 0, 0);
      }
    __builtin_amdgcn_s_setprio(0);
    BARF();

    // ---- ph1: B n2-3; stage B(T+1); MFMA m0-3 x n2-3
#pragma unroll
    for (int n = 0; n < 2; ++n) {
      bB[2 * n]     = *(const short8*)(b0 + (2 + n) * 2048);
      bB[2 * n + 1] = *(const short8*)(b1 + (2 + n) * 2048);
    }
    STG_B(bufn, Ts);
    BARF();
    __builtin_amdgcn_s_setprio(1);
#pragma unroll
    for (int m = 0; m < 4; ++m)
#pragma unroll
      for (int n = 0; n < 2; ++n) {
        acc[m][2 + n] = __builtin_amdgcn_mfma_f32_16x16x32_bf16(aF[2 * m], bB[2 * n], acc[m][2 + n], 0, 0, 0);
        acc[m][2 + n] = __builtin_amdgcn_mfma_f32_16x16x32_bf16(aF[2 * m + 1], bB[2 * n + 1], acc[m][2 + n], 0, 0, 0);
      }
    __builtin_amdgcn_s_setprio(0);
    BARF();

    // ---- ph2: A m4-7 (reuse aF regs); MFMA m4-7 x n2-3
#pragma unroll
    for (int m = 0; m < 4; ++m) {
      aF[2 * m]     = *(const short8*)(a0 + (4 + m) * 2048);
      aF[2 * m + 1] = *(const short8*)(a1 + (4 + m) * 2048);
    }
    BARF();
    __builtin_amdgcn_s_setprio(1);
#pragma unroll
    for (int m = 0; m < 4; ++m)
#pragma unroll
      for (int n = 0; n < 2; ++n) {
        acc[4 + m][2 + n] = __builtin_amdgcn_mfma_f32_16x16x32_bf16(aF[2 * m], bB[2 * n], acc[4 + m][2 + n], 0, 0, 0);
        acc[4 + m][2 + n] = __builtin_amdgcn_mfma_f32_16x16x32_bf16(aF[2 * m + 1], bB[2 * n + 1], acc[4 + m][2 + n], 0, 0, 0);
      }
    __builtin_amdgcn_s_setprio(0);
    BARF();

    // ---- ph3: certify next buffer (stages 2-3 phases old); MFMA m4-7 x n0-1
    asm volatile("s_waitcnt vmcnt(0)" ::: "memory");
    BARF();
    __builtin_amdgcn_s_setprio(1);
#pragma unroll
    for (int m = 0; m < 4; ++m)
#pragma unroll
      for (int n = 0; n < 2; ++n) {
        acc[4 + m][n] = __builtin_amdgcn_mfma_f32_16x16x32_bf16(aF[2 * m], bA[2 * n], acc[4 + m][n], 0, 0, 0);
        acc[4 + m][n] = __builtin_amdgcn_mfma_f32_16x16x32_bf16(aF[2 * m + 1], bA[2 * n + 1], acc[4 + m][n], 0, 0, 0);
      }
    __builtin_amdgcn_s_setprio(0);
    BARF();
  }
#undef STG_A
#undef STG_B
#undef BARF

  // ---- epilogue; C frag: col = lane&15, row = (lane>>4)*4 + r
  const int cRow0 = wr * 128 + (hi << 2);
  const int cColB = n0 + wc * 64 + l15;
  float bv[4];
#pragma unroll
  for (int nf = 0; nf < 4; ++nf) bv[nf] = bias[e * N + cColB + nf * 16];

  if (EPI == 1) {
    unsigned short* H = (unsigned short*)outp;
#pragma unroll
    for (int m = 0; m < 8; ++m)
#pragma unroll
      for (int r = 0; r < 4; ++r) {
        const int sl = cRow0 + m * 16 + r;
        if (row0 + sl < cnte) {
          const size_t rp = (size_t)(pre + row0 + sl) * N + cColB;
#pragma unroll
          for (int nf = 0; nf < 4; ++nf) {
            float v = acc[m][nf][r] + bv[nf];
            // tanh-form GELU via exp (dev <= ~1e-3 vs erf; threshold 3.4e-2)
            float u = 1.5957691216f * v * (1.0f + 0.044715f * v * v);
            float ex = __expf(u);
            float th = 1.0f - 2.0f / (ex + 1.0f);
            v = 0.5f * v * (1.0f + th);
            H[rp + nf * 16] = f2b(v);
          }
        }
      }
  } else {
    float* O = (float*)outp;
#pragma unroll
    for (int m = 0; m < 8; ++m)
#pragma unroll
      for (int r = 0; r < 4; ++r) {
        const int sl = cRow0 + m * 16 + r;
        if (row0 + sl < cnte) {
          const size_t rp = (size_t)tok_s[sl] * N + cColB;
          const float w = wt_s[sl];
#pragma unroll
          for (int nf = 0; nf < 4; ++nf)
            O[rp + nf * 16] = (acc[m][nf][r] + bv[nf]) * w;
        }
      }
  }
}

// ---------------------------------------------------------------------------
extern "C" void kernel_launch(void* const* d_in, const int* in_sizes, int n_in,
                              void* d_out, int out_size, void* d_ws, size_t ws_size,
                              hipStream_t stream) {
  const float* x  = (const float*)d_in[0];   // [4,4096,1024]
  const float* Wr = (const float*)d_in[1];   // [1024,8]
  const float* br = (const float*)d_in[2];   // [8]
  const float* W1 = (const float*)d_in[3];   // [8,1024,2048]
  const float* b1 = (const float*)d_in[4];   // [8,2048]
  const float* W2 = (const float*)d_in[5];   // [8,2048,1024]
  const float* b2 = (const float*)d_in[6];   // [8,1024]

  char* ws = (char*)d_ws;
  int*   cnt  = (int*)ws;                                  // 8 ints
  float* wts  = (float*)(ws + 256);                        // 16384 f32
  int*   eidx = (int*)(ws + 256 + 64 * 1024);              // 16384 int
  int*   list = (int*)(ws + 256 + 128 * 1024);             // 8*16384 int
  unsigned short* xb  = (unsigned short*)(ws + 1024 * 1024);     // 32 MB token rows
  unsigned short* w1t = xb  + (size_t)16384 * 1024;              // 32 MB
  unsigned short* w2t = w1t + (size_t)8 * 2048 * 1024;           // 32 MB
  unsigned short* h   = w2t + (size_t)8 * 1024 * 2048;           // 64 MB slot rows

  constexpr int LDS_BYTES = 133120;   // dbuf-2 256x256 + tok/wt, 1 block/CU
  hipFuncSetAttribute((const void*)gemm_moe8<1024, 2048, 1, 3>,
                      hipFuncAttributeMaxDynamicSharedMemorySize, LDS_BYTES);
  hipFuncSetAttribute((const void*)gemm_moe8<2048, 1024, 2, 2>,
                      hipFuncAttributeMaxDynamicSharedMemorySize, LDS_BYTES);

  hipMemsetAsync(cnt, 0, 32, stream);
  router_logits<<<dim3(4096), 256, 0, stream>>>(x, Wr, br, wts, eidx, xb);
  bucketize<<<dim3(64), 256, 0, stream>>>(eidx, cnt, list);
  transpose_cvt<<<dim3(32, 16, 8), 256, 0, stream>>>(W1, w1t, 1024, 2048);
  transpose_cvt<<<dim3(16, 32, 8), 256, 0, stream>>>(W2, w2t, 2048, 1024);
  // worst-case m-blocks: sum_e ceil(cnt_e/256) <= 64+7 = 71
  // grids must be divisible by 8 for the bijective XCD-chunked decode
  gemm_moe8<1024, 2048, 1, 3><<<dim3(71 * 8), 512, LDS_BYTES, stream>>>(
      xb, w1t, b1, cnt, list, wts, (void*)h);
  gemm_moe8<2048, 1024, 2, 2><<<dim3(72 * 4), 512, LDS_BYTES, stream>>>(
      h, w2t, b2, cnt, list, wts, d_out);
}

// Round 13
// 318.969 us; speedup vs baseline: 1.1295x; 1.1295x over previous
//
#include <hip/hip_runtime.h>
#include <hip/hip_bf16.h>

// Switch-Transformer FFN, top-1 routing. B=4,S=4096,D=1024,F=2048,E=8.
// Pipeline: router_logits(+x->bf16) | bucketize | W1/W2 transpose->bf16 |
// grouped GEMM1 (gathered A, GELU, h bf16 dense by slot) |
// grouped GEMM2 (dense A, scale epi, scatter fp32).
// GEMM: 128x128 tile, 4 waves (wave 64x64: FLOP/LDS-elem 32 vs 25.6 at
// 128x32), BK=32, ring-3 LDS (50KB -> 3 blocks/CU), counted vmcnt(4)
// (never drains in-loop), R10's proven single-barrier TILE_BODY.
// 4x block count -> ceil-tail shrinks (gemm1 ~92%, gemm2 ~69% packing).
// 0-conflict XOR swizzle. XCD-chunked nb-fast decode.

typedef __attribute__((ext_vector_type(8))) short short8;
typedef __attribute__((ext_vector_type(4))) float f32x4;

struct __align__(8) us4 { unsigned short x, y, z, w; };

__device__ __forceinline__ void gload16(const void* g, void* l) {
  __builtin_amdgcn_global_load_lds(
      (const __attribute__((address_space(1))) unsigned int*)g,
      (__attribute__((address_space(3))) unsigned int*)l, 16, 0, 0);
}

__device__ __forceinline__ unsigned short f2b(float f) {
  union { float f; unsigned u; } v; v.f = f;
  unsigned r = v.u + 0x7FFFu + ((v.u >> 16) & 1u);   // RNE
  return (unsigned short)(r >> 16);
}

// ---------------- router: logits, softmax top-1, expert id, x->bf16 ---------
__global__ __launch_bounds__(256) void router_logits(
    const float* __restrict__ x, const float* __restrict__ Wr,
    const float* __restrict__ br, float* __restrict__ wts,
    int* __restrict__ eidx, unsigned short* __restrict__ xb)
{
  const int lane = threadIdx.x & 63;
  const int wid  = threadIdx.x >> 6;
  const int t = blockIdx.x * 4 + wid;

  const float4* x4 = (const float4*)(x + (size_t)t * 1024);
  float acc[8];
#pragma unroll
  for (int e = 0; e < 8; ++e) acc[e] = 0.f;
#pragma unroll
  for (int i = 0; i < 4; ++i) {
    float4 v = x4[lane + 64 * i];
    const int d = (lane + 64 * i) * 4;
    const float* wr = Wr + (size_t)d * 8;
    float xs[4] = {v.x, v.y, v.z, v.w};
    us4 o;
    o.x = f2b(v.x); o.y = f2b(v.y); o.z = f2b(v.z); o.w = f2b(v.w);
    *(us4*)(xb + (size_t)t * 1024 + (size_t)(lane + 64 * i) * 4) = o;
#pragma unroll
    for (int j = 0; j < 4; ++j) {
      float4 w0 = *(const float4*)(wr + j * 8);
      float4 w1 = *(const float4*)(wr + j * 8 + 4);
      acc[0] += xs[j] * w0.x; acc[1] += xs[j] * w0.y;
      acc[2] += xs[j] * w0.z; acc[3] += xs[j] * w0.w;
      acc[4] += xs[j] * w1.x; acc[5] += xs[j] * w1.y;
      acc[6] += xs[j] * w1.z; acc[7] += xs[j] * w1.w;
    }
  }
#pragma unroll
  for (int e = 0; e < 8; ++e) {
    float v = acc[e];
#pragma unroll
    for (int m = 32; m; m >>= 1) v += __shfl_xor(v, m, 64);
    acc[e] = v;
  }
  if (lane == 0) {
    float lg[8];
#pragma unroll
    for (int e = 0; e < 8; ++e) lg[e] = acc[e] + br[e];
    float mx = lg[0]; int bi = 0;
#pragma unroll
    for (int e = 1; e < 8; ++e) if (lg[e] > mx) { mx = lg[e]; bi = e; }  // first-max == argmax
    float s = 0.f;
#pragma unroll
    for (int e = 0; e < 8; ++e) s += expf(lg[e] - mx);
    wts[t]  = 1.0f / s;
    eidx[t] = bi;
  }
}

// ---------------- bucketize ----------
__global__ __launch_bounds__(256) void bucketize(
    const int* __restrict__ eidx, int* __restrict__ cnt, int* __restrict__ list)
{
  __shared__ int lcnt[8], base[8];
  const int tid = threadIdx.x;
  if (tid < 8) lcnt[tid] = 0;
  __syncthreads();
  const int t = blockIdx.x * 256 + tid;
  const int e = eidx[t];
  const int lpos = atomicAdd(&lcnt[e], 1);
  __syncthreads();
  if (tid < 8) base[tid] = atomicAdd(&cnt[tid], lcnt[tid]);
  __syncthreads();
  list[e * 16384 + base[e] + lpos] = t;
}

// ---------------- W[k][n] fp32 -> Wt[n][k] bf16 ----------
__global__ __launch_bounds__(256) void transpose_cvt(
    const float* __restrict__ W, unsigned short* __restrict__ Wt, int K, int N)
{
  __shared__ float tl[64][65];
  const int e = blockIdx.z;
  const float* Wp = W + (size_t)e * K * N;
  unsigned short* Wtp = Wt + (size_t)e * K * N;
  const int k0 = blockIdx.y * 64, n0 = blockIdx.x * 64;
  const int r = threadIdx.x >> 4, c4 = (threadIdx.x & 15) * 4;
#pragma unroll
  for (int i = 0; i < 4; ++i) {
    float4 v = *(const float4*)(Wp + (size_t)(k0 + r + i * 16) * N + n0 + c4);
    tl[r + i * 16][c4 + 0] = v.x; tl[r + i * 16][c4 + 1] = v.y;
    tl[r + i * 16][c4 + 2] = v.z; tl[r + i * 16][c4 + 3] = v.w;
  }
  __syncthreads();
#pragma unroll
  for (int i = 0; i < 4; ++i) {
    const int n = r + i * 16;
    us4 o;
    o.x = f2b(tl[c4 + 0][n]); o.y = f2b(tl[c4 + 1][n]);
    o.z = f2b(tl[c4 + 2][n]); o.w = f2b(tl[c4 + 3][n]);
    *(us4*)(Wtp + (size_t)(n0 + n) * K + k0 + c4) = o;
  }
}

// ---------------- grouped GEMM: 128x128, BK=32, ring-3, 3 blocks/CU ---------
// LDS (50176 B): A slots 3x8KB @0; B slots 3x8KB @24576; tok@49152 wt@49664.
// Swizzle (measured 0-conflict): 16B-slot c of row r holds chunk c^((r>>1)&3).
// Iter T (slot SR=T%3, stage slot SS=(T+2)%3, compile-time via x3 unroll):
//   { STG A+B(tile T+2 -> SS) (4 gload issues) | 8 ds_read frags(T, SR) |
//     setprio(1) 16 MFMA (compiler counted-lgkm) setprio(0) | vmcnt(4) |
//     s_barrier | fence }.
// vmcnt(4): outstanding = tiles T+1,T+2 (8 issues) -> certifies tile T+1.
// Slot safety: write slot (T+2)%3 == read slot of iter T-1 (reads done
// before T-1 barrier). 4 waves/block: wave w -> 64x64 output quadrant.
template <int K, int N, int EPI, int LOGNB>
__global__ __launch_bounds__(256, 4) void gemm_moe8(
    const unsigned short* __restrict__ A,    // EPI1: xb[16384][K] (token rows)
                                             // EPI2: h [16384][K] (slot rows)
    const unsigned short* __restrict__ Bt,   // [8][N][K] bf16
    const float* __restrict__ bias,          // [8][N]
    const int* __restrict__ cnt, const int* __restrict__ list,
    const float* __restrict__ wts, void* __restrict__ outp)
{
  constexpr int NT = K / 32;
  constexpr int NB = 1 << LOGNB;
  extern __shared__ char lds[];
  int*   tok_s = (int*)(lds + 49152);
  float* wt_s  = (float*)(lds + 49664);

  // ---- decode: XCD-chunked p -> (expert, mb, nb); nb fast (A-panel reuse)
  const int q = gridDim.x >> 3;
  const int p = ((int)blockIdx.x & 7) * q + ((int)blockIdx.x >> 3);
  int e = -1, pre = 0, cnte = 0, loc = p;
#pragma unroll
  for (int i = 0; i < 8; ++i) {
    const int c = cnt[i];
    const int bl = ((c + 127) >> 7) << LOGNB;
    if (e < 0) {
      if (loc < bl) { e = i; cnte = c; }
      else { loc -= bl; pre += c; }
    }
  }
  if (e < 0) return;
  const int row0 = (loc >> LOGNB) << 7;      // BM=128
  const int n0   = (loc & (NB - 1)) << 7;    // BN=128

  const int tid = threadIdx.x;
  const int lane = tid & 63, wid = tid >> 6;
  const int wr = wid >> 1, wc = wid & 1;     // wave output: rows wr*64, cols wc*64
  const int l15 = lane & 15;

  if (tid < 128) {
    const int s = row0 + tid;
    if (s < cnte) {
      const int t = list[e * 16384 + s];
      tok_s[tid] = t;
      wt_s[tid]  = (EPI == 2) ? wts[t] : 0.f;
    } else { tok_s[tid] = 0; wt_s[tid] = 0.f; }
  }
  __syncthreads();

  // ---- staging: issue k2 covers rows k2*64 + (tid>>2), 16B slot (tid&3)
  const int srow = tid >> 2;                 // 0..63
  const int gch  = ((tid & 3) ^ ((srow >> 1) & 3)) * 8;   // pre-swizzled chunk
  const unsigned short* aP[2];
  const unsigned short* bP[2];
#pragma unroll
  for (int k2 = 0; k2 < 2; ++k2) {
    const int row = k2 * 64 + srow;
    if (EPI == 1) aP[k2] = A + (size_t)tok_s[row] * K + gch;
    else          aP[k2] = A + (size_t)min(pre + row0 + row, 16383) * K + gch;
    bP[k2] = Bt + ((size_t)e * N + n0 + row) * K + gch;
  }

  // ---- fragment read bases (XOR folds to per-lane constant)
  const int xo = (((lane >> 4) ^ ((l15 >> 1) & 3)) << 4);
  const char* aB = lds + (size_t)(wr * 64 + l15) * 64 + xo;          // + slot*8192 + m*1024
  const char* bB = lds + 24576 + (size_t)(wc * 64 + l15) * 64 + xo;  // + slot*8192 + n*1024

  f32x4 acc[4][4];
#pragma unroll
  for (int m = 0; m < 4; ++m)
#pragma unroll
    for (int n = 0; n < 4; ++n) acc[m][n] = (f32x4){0.f, 0.f, 0.f, 0.f};

#define STG_A(S, T) do { _Pragma("unroll") \
    for (int k2 = 0; k2 < 2; ++k2) \
      gload16(aP[k2] + (size_t)(T) * 32, lds + (S) * 8192 + k2 * 4096 + (wid << 10)); \
  } while (0)
#define STG_B(S, T) do { _Pragma("unroll") \
    for (int k2 = 0; k2 < 2; ++k2) \
      gload16(bP[k2] + (size_t)(T) * 32, lds + 24576 + (S) * 8192 + k2 * 4096 + (wid << 10)); \
  } while (0)

  // one subtile: stage tile T+2 into SS, read slot SR, MFMA, vmcnt(4), bar
#define TILE_BODY(T, SR, SS) do { \
    const int Ts_ = ((T) + 2 < NT) ? (T) + 2 : NT - 1;   /* dummy at tail */ \
    STG_A(SS, Ts_); \
    STG_B(SS, Ts_); \
    const char* aT = aB + (SR) * 8192; \
    const char* bT = bB + (SR) * 8192; \
    short8 aF[4], bF[4]; \
    _Pragma("unroll") \
    for (int m_ = 0; m_ < 4; ++m_) aF[m_] = *(const short8*)(aT + m_ * 1024); \
    _Pragma("unroll") \
    for (int n_ = 0; n_ < 4; ++n_) bF[n_] = *(const short8*)(bT + n_ * 1024); \
    __builtin_amdgcn_s_setprio(1); \
    _Pragma("unroll") \
    for (int m_ = 0; m_ < 4; ++m_) \
      _Pragma("unroll") \
      for (int n_ = 0; n_ < 4; ++n_) \
        acc[m_][n_] = __builtin_amdgcn_mfma_f32_16x16x32_bf16( \
            aF[m_], bF[n_], acc[m_][n_], 0, 0, 0); \
    __builtin_amdgcn_s_setprio(0); \
    asm volatile("s_waitcnt vmcnt(4)" ::: "memory");   /* certify tile T+1 */ \
    __builtin_amdgcn_s_barrier(); \
    asm volatile("" ::: "memory");   /* no ds_read hoists above barrier */ \
  } while (0)

  // ---- prologue: stage tiles 0,1 into slots 0,1; certify tile 0
  STG_A(0, 0); STG_B(0, 0);
  STG_A(1, 1); STG_B(1, 1);
  asm volatile("s_waitcnt vmcnt(4)" ::: "memory");   // tile 0 landed
  __builtin_amdgcn_s_barrier();
  asm volatile("" ::: "memory");

#pragma unroll 1
  for (int T = 0; T < NT; T += 3) {                  // slots compile-time
    TILE_BODY(T, 0, 2);
    if (T + 1 < NT) TILE_BODY(T + 1, 1, 0);
    if (T + 2 < NT) TILE_BODY(T + 2, 2, 1);
  }
#undef TILE_BODY
#undef STG_A
#undef STG_B
  asm volatile("s_waitcnt vmcnt(0)" ::: "memory");   // drain dummy stages

  // ---- epilogue; C frag: col = lane&15, row = (lane>>4)*4 + r
  const int cRow0 = wr * 64 + ((lane >> 4) << 2);
  const int cColB = n0 + wc * 64 + l15;
  float bv[4];
#pragma unroll
  for (int nf = 0; nf < 4; ++nf) bv[nf] = bias[e * N + cColB + nf * 16];

  if (EPI == 1) {
    unsigned short* H = (unsigned short*)outp;
#pragma unroll
    for (int m = 0; m < 4; ++m)
#pragma unroll
      for (int r = 0; r < 4; ++r) {
        const int sl = cRow0 + m * 16 + r;
        if (row0 + sl < cnte) {
          const size_t rp = (size_t)(pre + row0 + sl) * N + cColB;
#pragma unroll
          for (int nf = 0; nf < 4; ++nf) {
            float v = acc[m][nf][r] + bv[nf];
            // tanh-form GELU via exp (dev <= ~1e-3 vs erf; threshold 3.4e-2)
            float u = 1.5957691216f * v * (1.0f + 0.044715f * v * v);
            float ex = __expf(u);
            float th = 1.0f - 2.0f / (ex + 1.0f);
            v = 0.5f * v * (1.0f + th);
            H[rp + nf * 16] = f2b(v);
          }
        }
      }
  } else {
    float* O = (float*)outp;
#pragma unroll
    for (int m = 0; m < 4; ++m)
#pragma unroll
      for (int r = 0; r < 4; ++r) {
        const int sl = cRow0 + m * 16 + r;
        if (row0 + sl < cnte) {
          const size_t rp = (size_t)tok_s[sl] * N + cColB;
          const float w = wt_s[sl];
#pragma unroll
          for (int nf = 0; nf < 4; ++nf)
            O[rp + nf * 16] = (acc[m][nf][r] + bv[nf]) * w;
        }
      }
  }
}

// ---------------------------------------------------------------------------
extern "C" void kernel_launch(void* const* d_in, const int* in_sizes, int n_in,
                              void* d_out, int out_size, void* d_ws, size_t ws_size,
                              hipStream_t stream) {
  const float* x  = (const float*)d_in[0];   // [4,4096,1024]
  const float* Wr = (const float*)d_in[1];   // [1024,8]
  const float* br = (const float*)d_in[2];   // [8]
  const float* W1 = (const float*)d_in[3];   // [8,1024,2048]
  const float* b1 = (const float*)d_in[4];   // [8,2048]
  const float* W2 = (const float*)d_in[5];   // [8,2048,1024]
  const float* b2 = (const float*)d_in[6];   // [8,1024]

  char* ws = (char*)d_ws;
  int*   cnt  = (int*)ws;                                  // 8 ints
  float* wts  = (float*)(ws + 256);                        // 16384 f32
  int*   eidx = (int*)(ws + 256 + 64 * 1024);              // 16384 int
  int*   list = (int*)(ws + 256 + 128 * 1024);             // 8*16384 int
  unsigned short* xb  = (unsigned short*)(ws + 1024 * 1024);     // 32 MB token rows
  unsigned short* w1t = xb  + (size_t)16384 * 1024;              // 32 MB
  unsigned short* w2t = w1t + (size_t)8 * 2048 * 1024;           // 32 MB
  unsigned short* h   = w2t + (size_t)8 * 1024 * 2048;           // 64 MB slot rows

  constexpr int LDS_BYTES = 50176;   // ring-3 128^2 + tok/wt -> 3 blocks/CU
  hipFuncSetAttribute((const void*)gemm_moe8<1024, 2048, 1, 4>,
                      hipFuncAttributeMaxDynamicSharedMemorySize, LDS_BYTES);
  hipFuncSetAttribute((const void*)gemm_moe8<2048, 1024, 2, 3>,
                      hipFuncAttributeMaxDynamicSharedMemorySize, LDS_BYTES);

  hipMemsetAsync(cnt, 0, 32, stream);
  router_logits<<<dim3(4096), 256, 0, stream>>>(x, Wr, br, wts, eidx, xb);
  bucketize<<<dim3(64), 256, 0, stream>>>(eidx, cnt, list);
  transpose_cvt<<<dim3(32, 16, 8), 256, 0, stream>>>(W1, w1t, 1024, 2048);
  transpose_cvt<<<dim3(16, 32, 8), 256, 0, stream>>>(W2, w2t, 2048, 1024);
  // worst-case m-blocks: sum_e ceil(cnt_e/128) <= 128+7 = 135
  // grids divisible by 8 for the XCD-chunked decode
  gemm_moe8<1024, 2048, 1, 4><<<dim3(135 * 16), 256, LDS_BYTES, stream>>>(
      xb, w1t, b1, cnt, list, wts, (void*)h);
  gemm_moe8<2048, 1024, 2, 3><<<dim3(135 * 8), 256, LDS_BYTES, stream>>>(
      h, w2t, b2, cnt, list, wts, d_out);
}